// Round 1
// baseline (141.714 us; speedup 1.0000x reference)
//
#include <hip/hip_runtime.h>

// RelationModule: out = ((psi @ M - diag(psi·phi)·u) / N) @ w_r + x
// where M[b] = phi[b]^T @ u[b]  (F×F per batch) — avoids the O(N^2) score matrix.
//
// B=32, N=2048, F=32. fp32 throughout.

namespace {
constexpr int kF = 32;
constexpr int kN = 2048;
constexpr int kB = 32;

constexpr int kChunk1 = 128;              // elements per k_partial_m block (128 threads)
constexpr int kNChunk1 = kN / kChunk1;    // 16
constexpr int kChunk2 = 256;              // elements per k_relation block (256 threads)
constexpr int kNChunk2 = kN / kChunk2;    // 8

constexpr int kPad = 36;                  // LDS row stride (floats): 144 B, 16B-aligned,
                                          // breaks the stride-32 bank-conflict pathology
}

// ---------------------------------------------------------------------------
// Kernel 1: per-batch M = phi^T @ relu(u), accumulated via atomicAdd partials.
// Grid (kNChunk1, kB), 128 threads. Phase A: thread-per-element embeddings.
// Phase B: thread-per-(f,g8) outer-product reduction over the 128-elem tile.
// ---------------------------------------------------------------------------
__global__ __launch_bounds__(128) void k_partial_m(
    const float* __restrict__ x,
    const float* __restrict__ w_phi, const float* __restrict__ b_phi,
    const float* __restrict__ w_u,   const float* __restrict__ b_u,
    float* __restrict__ m_out)  // [kB][kF*kF], pre-zeroed
{
    __shared__ float wphi_s[kF * kF];
    __shared__ float wu_s[kF * kF];
    __shared__ float bias_s[2 * kF];
    __shared__ float phi_s[kChunk1 * kPad];
    __shared__ float u_s[kChunk1 * kPad];

    const int tid = threadIdx.x;
    const int c = blockIdx.x;
    const int b = blockIdx.y;

    for (int i = tid; i < kF * kF; i += 128) {
        wphi_s[i] = w_phi[i];
        wu_s[i] = w_u[i];
    }
    if (tid < kF) {
        bias_s[tid] = b_phi[tid];
        bias_s[kF + tid] = b_u[tid];
    }
    __syncthreads();

    // ---- Phase A: one thread per element: phi_j, relu(u_j) -> LDS ----
    const size_t base = ((size_t)b * kN + (size_t)c * kChunk1 + tid) * kF;
    float xs[kF];
#pragma unroll
    for (int k = 0; k < kF / 4; ++k) {
        float4 v = ((const float4*)(x + base))[k];
        xs[4 * k + 0] = v.x; xs[4 * k + 1] = v.y;
        xs[4 * k + 2] = v.z; xs[4 * k + 3] = v.w;
    }

    float ph[kF], uu[kF];
#pragma unroll
    for (int g = 0; g < kF; ++g) {
        ph[g] = bias_s[g];
        uu[g] = bias_s[kF + g];
    }
#pragma unroll
    for (int f = 0; f < kF; ++f) {
        const float xf = xs[f];
#pragma unroll
        for (int g4 = 0; g4 < kF / 4; ++g4) {
            const float4 w1 = *((const float4*)(wphi_s + f * kF) + g4);  // uniform -> broadcast
            const float4 w2 = *((const float4*)(wu_s + f * kF) + g4);
            ph[4 * g4 + 0] += xf * w1.x; ph[4 * g4 + 1] += xf * w1.y;
            ph[4 * g4 + 2] += xf * w1.z; ph[4 * g4 + 3] += xf * w1.w;
            uu[4 * g4 + 0] += xf * w2.x; uu[4 * g4 + 1] += xf * w2.y;
            uu[4 * g4 + 2] += xf * w2.z; uu[4 * g4 + 3] += xf * w2.w;
        }
    }

    float* prow = phi_s + tid * kPad;
    float* urow = u_s + tid * kPad;
#pragma unroll
    for (int g4 = 0; g4 < kF / 4; ++g4) {
        float4 pv = make_float4(ph[4 * g4], ph[4 * g4 + 1], ph[4 * g4 + 2], ph[4 * g4 + 3]);
        float4 uv = make_float4(fmaxf(uu[4 * g4], 0.f), fmaxf(uu[4 * g4 + 1], 0.f),
                                fmaxf(uu[4 * g4 + 2], 0.f), fmaxf(uu[4 * g4 + 3], 0.f));
        *((float4*)prow + g4) = pv;   // row stride 144B: banks rotate, only mild conflicts
        *((float4*)urow + g4) = uv;
    }
    __syncthreads();

    // ---- Phase B: thread -> (f, 8 consecutive g). 32*4 = 128 threads cover 32x32 ----
    const int f = tid & (kF - 1);
    const int g8 = (tid >> 5) * 8;  // 0,8,16,24
    float acc[8];
#pragma unroll
    for (int k = 0; k < 8; ++k) acc[k] = 0.f;

#pragma unroll 8
    for (int j = 0; j < kChunk1; ++j) {
        const float p = phi_s[j * kPad + f];                     // stride-1 over lanes
        const float4 u0 = *(const float4*)(u_s + j * kPad + g8);     // 2 addrs/wave -> bcast
        const float4 u1 = *(const float4*)(u_s + j * kPad + g8 + 4);
        acc[0] += p * u0.x; acc[1] += p * u0.y; acc[2] += p * u0.z; acc[3] += p * u0.w;
        acc[4] += p * u1.x; acc[5] += p * u1.y; acc[6] += p * u1.z; acc[7] += p * u1.w;
    }

    float* mdst = m_out + (size_t)b * kF * kF + f * kF + g8;
#pragma unroll
    for (int k = 0; k < 8; ++k) atomicAdd(mdst + k, acc[k]);  // 16 chunks contend per addr
}

// ---------------------------------------------------------------------------
// Kernel 2: thread-per-element: psi, phi, u, att = psi@M - diag*u,
//           out = (att/N) @ w_r + x.  Grid (kNChunk2, kB), 256 threads.
// ---------------------------------------------------------------------------
__global__ __launch_bounds__(256) void k_relation(
    const float* __restrict__ x,
    const float* __restrict__ w_psi, const float* __restrict__ b_psi,
    const float* __restrict__ w_phi, const float* __restrict__ b_phi,
    const float* __restrict__ w_u,   const float* __restrict__ b_u,
    const float* __restrict__ w_r,
    const float* __restrict__ m_in,   // [kB][kF*kF]
    float* __restrict__ out)
{
    __shared__ float wpsi_s[kF * kF];
    __shared__ float wphi_s[kF * kF];
    __shared__ float wu_s[kF * kF];
    __shared__ float wr_s[kF * kF];
    __shared__ float m_s[kF * kF];
    __shared__ float bias_s[3 * kF];

    const int tid = threadIdx.x;
    const int c = blockIdx.x;
    const int b = blockIdx.y;

    for (int i = tid; i < kF * kF; i += 256) {
        wpsi_s[i] = w_psi[i];
        wphi_s[i] = w_phi[i];
        wu_s[i] = w_u[i];
        wr_s[i] = w_r[i];
        m_s[i] = m_in[(size_t)b * kF * kF + i];
    }
    if (tid < kF) {
        bias_s[tid] = b_psi[tid];
        bias_s[kF + tid] = b_phi[tid];
        bias_s[2 * kF + tid] = b_u[tid];
    }
    __syncthreads();

    const size_t base = ((size_t)b * kN + (size_t)c * kChunk2 + tid) * kF;
    float xs[kF];
#pragma unroll
    for (int k = 0; k < kF / 4; ++k) {
        float4 v = ((const float4*)(x + base))[k];
        xs[4 * k + 0] = v.x; xs[4 * k + 1] = v.y;
        xs[4 * k + 2] = v.z; xs[4 * k + 3] = v.w;
    }

    // psi = x @ w_psi + b_psi
    float ps[kF];
#pragma unroll
    for (int g = 0; g < kF; ++g) ps[g] = bias_s[g];
#pragma unroll
    for (int f = 0; f < kF; ++f) {
        const float xf = xs[f];
#pragma unroll
        for (int g4 = 0; g4 < kF / 4; ++g4) {
            const float4 w = *((const float4*)(wpsi_s + f * kF) + g4);
            ps[4 * g4 + 0] += xf * w.x; ps[4 * g4 + 1] += xf * w.y;
            ps[4 * g4 + 2] += xf * w.z; ps[4 * g4 + 3] += xf * w.w;
        }
    }

    // phi = x @ w_phi + b_phi ; diag = psi . phi
    float ph[kF];
#pragma unroll
    for (int g = 0; g < kF; ++g) ph[g] = bias_s[kF + g];
#pragma unroll
    for (int f = 0; f < kF; ++f) {
        const float xf = xs[f];
#pragma unroll
        for (int g4 = 0; g4 < kF / 4; ++g4) {
            const float4 w = *((const float4*)(wphi_s + f * kF) + g4);
            ph[4 * g4 + 0] += xf * w.x; ph[4 * g4 + 1] += xf * w.y;
            ph[4 * g4 + 2] += xf * w.z; ph[4 * g4 + 3] += xf * w.w;
        }
    }
    float diag = 0.f;
#pragma unroll
    for (int g = 0; g < kF; ++g) diag += ps[g] * ph[g];

    // u = relu(x @ w_u + b_u)   (reuses ph's registers once ph is dead)
    float uu[kF];
#pragma unroll
    for (int g = 0; g < kF; ++g) uu[g] = bias_s[2 * kF + g];
#pragma unroll
    for (int f = 0; f < kF; ++f) {
        const float xf = xs[f];
#pragma unroll
        for (int g4 = 0; g4 < kF / 4; ++g4) {
            const float4 w = *((const float4*)(wu_s + f * kF) + g4);
            uu[4 * g4 + 0] += xf * w.x; uu[4 * g4 + 1] += xf * w.y;
            uu[4 * g4 + 2] += xf * w.z; uu[4 * g4 + 3] += xf * w.w;
        }
    }
#pragma unroll
    for (int g = 0; g < kF; ++g) uu[g] = fmaxf(uu[g], 0.f);

    // att = psi @ M - diag * u
    float at[kF];
#pragma unroll
    for (int g = 0; g < kF; ++g) at[g] = -diag * uu[g];
#pragma unroll
    for (int f = 0; f < kF; ++f) {
        const float psf = ps[f];
#pragma unroll
        for (int g4 = 0; g4 < kF / 4; ++g4) {
            const float4 w = *((const float4*)(m_s + f * kF) + g4);
            at[4 * g4 + 0] += psf * w.x; at[4 * g4 + 1] += psf * w.y;
            at[4 * g4 + 2] += psf * w.z; at[4 * g4 + 3] += psf * w.w;
        }
    }

    // out = (att / N) @ w_r + x
    const float inv_n = 1.0f / (float)kN;
    float ot[kF];
#pragma unroll
    for (int f = 0; f < kF; ++f) ot[f] = xs[f];
#pragma unroll
    for (int g = 0; g < kF; ++g) {
        const float ag = at[g] * inv_n;
#pragma unroll
        for (int f4 = 0; f4 < kF / 4; ++f4) {
            const float4 w = *((const float4*)(wr_s + g * kF) + f4);
            ot[4 * f4 + 0] += ag * w.x; ot[4 * f4 + 1] += ag * w.y;
            ot[4 * f4 + 2] += ag * w.z; ot[4 * f4 + 3] += ag * w.w;
        }
    }

#pragma unroll
    for (int k = 0; k < kF / 4; ++k) {
        float4 v = make_float4(ot[4 * k], ot[4 * k + 1], ot[4 * k + 2], ot[4 * k + 3]);
        ((float4*)(out + base))[k] = v;
    }
}

extern "C" void kernel_launch(void* const* d_in, const int* in_sizes, int n_in,
                              void* d_out, int out_size, void* d_ws, size_t ws_size,
                              hipStream_t stream) {
    const float* x     = (const float*)d_in[0];
    const float* w_psi = (const float*)d_in[1];
    const float* b_psi = (const float*)d_in[2];
    const float* w_phi = (const float*)d_in[3];
    const float* b_phi = (const float*)d_in[4];
    const float* w_u   = (const float*)d_in[5];
    const float* b_u   = (const float*)d_in[6];
    const float* w_r   = (const float*)d_in[7];
    float* out = (float*)d_out;
    float* m_ws = (float*)d_ws;  // kB * kF * kF floats = 128 KiB

    // d_ws is poisoned 0xAA before every timed launch — zero the M accumulators.
    hipMemsetAsync(d_ws, 0, (size_t)kB * kF * kF * sizeof(float), stream);

    k_partial_m<<<dim3(kNChunk1, kB), 128, 0, stream>>>(
        x, w_phi, b_phi, w_u, b_u, m_ws);
    k_relation<<<dim3(kNChunk2, kB), 256, 0, stream>>>(
        x, w_psi, b_psi, w_phi, b_phi, w_u, b_u, w_r, m_ws, out);
}

// Round 2
// 138.118 us; speedup vs baseline: 1.0260x; 1.0260x over previous
//
#include <hip/hip_runtime.h>

// RelationModule: out = ((psi @ M - diag(psi·phi)·u) / N) @ w_r + x
// where M[b] = phi[b]^T @ u[b]  (F×F per batch) — avoids the O(N^2) score matrix.
//
// B=32, N=2048, F=32. fp32 throughout.
//
// R2: __launch_bounds__(.,1) — occupancy is grid-limited at 1 wave/SIMD
// (B*N = 1024 waves over 256 CUs), so capping VGPRs at 64 (R1, implicit)
// only caused remat/spill stalls (VALUBusy 18%, runtime 10x the VALU
// cycle count). Free the register budget; fuse psi/phi/u into one f-loop
// for 96 independent FMA chains per LDS-read batch.

namespace {
constexpr int kF = 32;
constexpr int kN = 2048;
constexpr int kB = 32;

constexpr int kChunk1 = 128;              // elements per k_partial_m block (128 threads)
constexpr int kNChunk1 = kN / kChunk1;    // 16
constexpr int kChunk2 = 256;              // elements per k_relation block (256 threads)
constexpr int kNChunk2 = kN / kChunk2;    // 8

constexpr int kPad = 36;                  // LDS row stride (floats): 144 B, 16B-aligned,
                                          // breaks the stride-32 bank-conflict pathology
}

// ---------------------------------------------------------------------------
// Kernel 1: per-batch M = phi^T @ relu(u), accumulated via atomicAdd partials.
// Grid (kNChunk1, kB), 128 threads. Phase A: thread-per-element embeddings.
// Phase B: thread-per-(f,g8) outer-product reduction over the 128-elem tile.
// ---------------------------------------------------------------------------
__global__ __launch_bounds__(128, 1) void k_partial_m(
    const float* __restrict__ x,
    const float* __restrict__ w_phi, const float* __restrict__ b_phi,
    const float* __restrict__ w_u,   const float* __restrict__ b_u,
    float* __restrict__ m_out)  // [kB][kF*kF], pre-zeroed
{
    __shared__ float wphi_s[kF * kF];
    __shared__ float wu_s[kF * kF];
    __shared__ float bias_s[2 * kF];
    __shared__ float phi_s[kChunk1 * kPad];
    __shared__ float u_s[kChunk1 * kPad];

    const int tid = threadIdx.x;
    const int c = blockIdx.x;
    const int b = blockIdx.y;

    for (int i = tid; i < kF * kF; i += 128) {
        wphi_s[i] = w_phi[i];
        wu_s[i] = w_u[i];
    }
    if (tid < kF) {
        bias_s[tid] = b_phi[tid];
        bias_s[kF + tid] = b_u[tid];
    }
    __syncthreads();

    // ---- Phase A: one thread per element: phi_j, relu(u_j) -> LDS ----
    const size_t base = ((size_t)b * kN + (size_t)c * kChunk1 + tid) * kF;
    float xs[kF];
#pragma unroll
    for (int k = 0; k < kF / 4; ++k) {
        float4 v = ((const float4*)(x + base))[k];
        xs[4 * k + 0] = v.x; xs[4 * k + 1] = v.y;
        xs[4 * k + 2] = v.z; xs[4 * k + 3] = v.w;
    }

    float ph[kF], uu[kF];
#pragma unroll
    for (int g = 0; g < kF; ++g) {
        ph[g] = bias_s[g];
        uu[g] = bias_s[kF + g];
    }
#pragma unroll
    for (int f = 0; f < kF; ++f) {
        const float xf = xs[f];
#pragma unroll
        for (int g4 = 0; g4 < kF / 4; ++g4) {
            const float4 w1 = *((const float4*)(wphi_s + f * kF) + g4);  // uniform -> broadcast
            const float4 w2 = *((const float4*)(wu_s + f * kF) + g4);
            ph[4 * g4 + 0] += xf * w1.x; ph[4 * g4 + 1] += xf * w1.y;
            ph[4 * g4 + 2] += xf * w1.z; ph[4 * g4 + 3] += xf * w1.w;
            uu[4 * g4 + 0] += xf * w2.x; uu[4 * g4 + 1] += xf * w2.y;
            uu[4 * g4 + 2] += xf * w2.z; uu[4 * g4 + 3] += xf * w2.w;
        }
    }

    float* prow = phi_s + tid * kPad;
    float* urow = u_s + tid * kPad;
#pragma unroll
    for (int g4 = 0; g4 < kF / 4; ++g4) {
        float4 pv = make_float4(ph[4 * g4], ph[4 * g4 + 1], ph[4 * g4 + 2], ph[4 * g4 + 3]);
        float4 uv = make_float4(fmaxf(uu[4 * g4], 0.f), fmaxf(uu[4 * g4 + 1], 0.f),
                                fmaxf(uu[4 * g4 + 2], 0.f), fmaxf(uu[4 * g4 + 3], 0.f));
        *((float4*)prow + g4) = pv;   // row stride 144B: banks rotate, only mild conflicts
        *((float4*)urow + g4) = uv;
    }
    __syncthreads();

    // ---- Phase B: thread -> (f, 8 consecutive g). 32*4 = 128 threads cover 32x32 ----
    const int f = tid & (kF - 1);
    const int g8 = (tid >> 5) * 8;  // 0,8,16,24
    float acc[8];
#pragma unroll
    for (int k = 0; k < 8; ++k) acc[k] = 0.f;

#pragma unroll 8
    for (int j = 0; j < kChunk1; ++j) {
        const float p = phi_s[j * kPad + f];                     // stride-1 over lanes
        const float4 u0 = *(const float4*)(u_s + j * kPad + g8);     // 2 addrs/wave -> bcast
        const float4 u1 = *(const float4*)(u_s + j * kPad + g8 + 4);
        acc[0] += p * u0.x; acc[1] += p * u0.y; acc[2] += p * u0.z; acc[3] += p * u0.w;
        acc[4] += p * u1.x; acc[5] += p * u1.y; acc[6] += p * u1.z; acc[7] += p * u1.w;
    }

    float* mdst = m_out + (size_t)b * kF * kF + f * kF + g8;
#pragma unroll
    for (int k = 0; k < 8; ++k) atomicAdd(mdst + k, acc[k]);  // 16 chunks contend per addr
}

// ---------------------------------------------------------------------------
// Kernel 2: thread-per-element: psi, phi, u, att = psi@M - diag*u,
//           out = (att/N) @ w_r + x.  Grid (kNChunk2, kB), 256 threads.
// R2: one fused f-loop for psi/phi/u (96 indep chains), out accumulated
// in-place into xs. Peak live set ~ xs+ps+ph+uu = 128 regs + addressing.
// ---------------------------------------------------------------------------
__global__ __launch_bounds__(256, 1) void k_relation(
    const float* __restrict__ x,
    const float* __restrict__ w_psi, const float* __restrict__ b_psi,
    const float* __restrict__ w_phi, const float* __restrict__ b_phi,
    const float* __restrict__ w_u,   const float* __restrict__ b_u,
    const float* __restrict__ w_r,
    const float* __restrict__ m_in,   // [kB][kF*kF]
    float* __restrict__ out)
{
    __shared__ float wpsi_s[kF * kF];
    __shared__ float wphi_s[kF * kF];
    __shared__ float wu_s[kF * kF];
    __shared__ float wr_s[kF * kF];
    __shared__ float m_s[kF * kF];
    __shared__ float bias_s[3 * kF];

    const int tid = threadIdx.x;
    const int c = blockIdx.x;
    const int b = blockIdx.y;

    for (int i = tid; i < kF * kF; i += 256) {
        wpsi_s[i] = w_psi[i];
        wphi_s[i] = w_phi[i];
        wu_s[i] = w_u[i];
        wr_s[i] = w_r[i];
        m_s[i] = m_in[(size_t)b * kF * kF + i];
    }
    if (tid < kF) {
        bias_s[tid] = b_psi[tid];
        bias_s[kF + tid] = b_phi[tid];
        bias_s[2 * kF + tid] = b_u[tid];
    }
    __syncthreads();

    const size_t base = ((size_t)b * kN + (size_t)c * kChunk2 + tid) * kF;
    float xs[kF];
#pragma unroll
    for (int k = 0; k < kF / 4; ++k) {
        float4 v = ((const float4*)(x + base))[k];
        xs[4 * k + 0] = v.x; xs[4 * k + 1] = v.y;
        xs[4 * k + 2] = v.z; xs[4 * k + 3] = v.w;
    }

    // ---- fused: psi, phi, u in one f-loop (96 independent FMA chains) ----
    float ps[kF], ph[kF], uu[kF];
#pragma unroll
    for (int g = 0; g < kF; ++g) {
        ps[g] = bias_s[g];
        ph[g] = bias_s[kF + g];
        uu[g] = bias_s[2 * kF + g];
    }
#pragma unroll
    for (int f = 0; f < kF; ++f) {
        const float xf = xs[f];
#pragma unroll
        for (int g4 = 0; g4 < kF / 4; ++g4) {
            const float4 w1 = *((const float4*)(wpsi_s + f * kF) + g4);
            const float4 w2 = *((const float4*)(wphi_s + f * kF) + g4);
            const float4 w3 = *((const float4*)(wu_s + f * kF) + g4);
            ps[4 * g4 + 0] += xf * w1.x; ps[4 * g4 + 1] += xf * w1.y;
            ps[4 * g4 + 2] += xf * w1.z; ps[4 * g4 + 3] += xf * w1.w;
            ph[4 * g4 + 0] += xf * w2.x; ph[4 * g4 + 1] += xf * w2.y;
            ph[4 * g4 + 2] += xf * w2.z; ph[4 * g4 + 3] += xf * w2.w;
            uu[4 * g4 + 0] += xf * w3.x; uu[4 * g4 + 1] += xf * w3.y;
            uu[4 * g4 + 2] += xf * w3.z; uu[4 * g4 + 3] += xf * w3.w;
        }
    }

    // diag = psi . phi ; u = relu(u). ph dead after this.
    float diag = 0.f;
#pragma unroll
    for (int g = 0; g < kF; ++g) diag += ps[g] * ph[g];
#pragma unroll
    for (int g = 0; g < kF; ++g) uu[g] = fmaxf(uu[g], 0.f);

    // att = psi @ M - diag * u   (reuses uu's storage conceptually; at[] fresh)
    float at[kF];
#pragma unroll
    for (int g = 0; g < kF; ++g) at[g] = -diag * uu[g];
#pragma unroll
    for (int f = 0; f < kF; ++f) {
        const float psf = ps[f];
#pragma unroll
        for (int g4 = 0; g4 < kF / 4; ++g4) {
            const float4 w = *((const float4*)(m_s + f * kF) + g4);
            at[4 * g4 + 0] += psf * w.x; at[4 * g4 + 1] += psf * w.y;
            at[4 * g4 + 2] += psf * w.z; at[4 * g4 + 3] += psf * w.w;
        }
    }

    // out = (att / N) @ w_r + x  — accumulate in place into xs
    const float inv_n = 1.0f / (float)kN;
#pragma unroll
    for (int g = 0; g < kF; ++g) {
        const float ag = at[g] * inv_n;
#pragma unroll
        for (int f4 = 0; f4 < kF / 4; ++f4) {
            const float4 w = *((const float4*)(wr_s + g * kF) + f4);
            xs[4 * f4 + 0] += ag * w.x; xs[4 * f4 + 1] += ag * w.y;
            xs[4 * f4 + 2] += ag * w.z; xs[4 * f4 + 3] += ag * w.w;
        }
    }

#pragma unroll
    for (int k = 0; k < kF / 4; ++k) {
        float4 v = make_float4(xs[4 * k], xs[4 * k + 1], xs[4 * k + 2], xs[4 * k + 3]);
        ((float4*)(out + base))[k] = v;
    }
}

extern "C" void kernel_launch(void* const* d_in, const int* in_sizes, int n_in,
                              void* d_out, int out_size, void* d_ws, size_t ws_size,
                              hipStream_t stream) {
    const float* x     = (const float*)d_in[0];
    const float* w_psi = (const float*)d_in[1];
    const float* b_psi = (const float*)d_in[2];
    const float* w_phi = (const float*)d_in[3];
    const float* b_phi = (const float*)d_in[4];
    const float* w_u   = (const float*)d_in[5];
    const float* b_u   = (const float*)d_in[6];
    const float* w_r   = (const float*)d_in[7];
    float* out = (float*)d_out;
    float* m_ws = (float*)d_ws;  // kB * kF * kF floats = 128 KiB

    // d_ws is poisoned 0xAA before every timed launch — zero the M accumulators.
    hipMemsetAsync(d_ws, 0, (size_t)kB * kF * kF * sizeof(float), stream);

    k_partial_m<<<dim3(kNChunk1, kB), 128, 0, stream>>>(
        x, w_phi, b_phi, w_u, b_u, m_ws);
    k_relation<<<dim3(kNChunk2, kB), 256, 0, stream>>>(
        x, w_psi, b_psi, w_phi, b_phi, w_u, b_u, w_r, m_ws, out);
}